// Round 12
// baseline (18.098 us; speedup 1.0000x reference)
//
#include <hip/hip_runtime.h>

// (B, S, H) = (8, 2048, 1024), fp32.
// Degenerate math: scores == 1/S exactly (softmax of a constant vector);
// context[b,h] == mean_s enc[b,s,h]; decoder_state cancels entirely.
// Lessons: R2 — grid.sync() ~200us; R3 — contended atomics; R4 — wide
//   finalize; R5 — shallower+more blocks regressed; R6/R9 — SGB & VGPR
//   budget null; R7/R8 — single-dispatch coherence 10x worse; R10 — 512
//   deep blocks + 2 MiB partials: 19.06 -> 17.39us (WIN, continuous issue).
// R11: one more halving — 256 blocks x 64-row chunks (8x8-deep passes),
//   partials 1 MiB. 4 waves/CU; fill kernel proves 2.8 waves/CU streams
//   6.8 TB/s, so latency still covered.
#define BB 8
#define SS 2048
#define HH 1024
#define NCHUNK 32            // S-chunks per batch
#define CHUNK (SS / NCHUNK)  // 64 rows per block
#define NBLK (BB * NCHUNK)   // 256 blocks

// Kernel A: block g=(b,c) sums its 64-row chunk; thread t owns float4 column
// h=4t..4t+3. 8 passes x 8 independent loads, fully unrolled -> long
// continuous-issue window; launch_bounds(256,4) = 128-VGPR budget.
__global__ void __launch_bounds__(256, 4)
att_partial_kernel(const float* __restrict__ enc, float* __restrict__ partial) {
    const int g = blockIdx.x;
    const int b = g >> 5;            // / NCHUNK
    const int c = g & (NCHUNK - 1);
    const int t = threadIdx.x;
    const float4* p =
        (const float4*)(enc + ((size_t)b * SS + (size_t)c * CHUNK) * HH) + t;

    float4 acc = make_float4(0.f, 0.f, 0.f, 0.f);
    #pragma unroll
    for (int pass = 0; pass < 8; ++pass) {
        float4 v[8];
        #pragma unroll
        for (int s = 0; s < 8; ++s)
            v[s] = p[(size_t)(pass * 8 + s) * (HH / 4)];
        #pragma unroll
        for (int st = 4; st > 0; st >>= 1) {
            #pragma unroll
            for (int s = 0; s < st; ++s) {
                v[s].x += v[s + st].x; v[s].y += v[s + st].y;
                v[s].z += v[s + st].z; v[s].w += v[s + st].w;
            }
        }
        acc.x += v[0].x; acc.y += v[0].y; acc.z += v[0].z; acc.w += v[0].w;
    }
    ((float4*)(partial + (size_t)g * HH))[t] = acc;  // g == b*NCHUNK + c
}

// Kernel B: 128 blocks x 256 threads. Block = (b, 64-wide h slice); wave cq
// sums chunks c = cq*8..cq*8+7 (coalesced 256 B/wave reads), LDS[4][64]
// cross-wave combine; fills 128 scores per block.
__global__ void __launch_bounds__(256)
att_finalize_kernel(const float* __restrict__ partial, float* __restrict__ out) {
    const int blk = blockIdx.x;        // 0..127
    const int b = blk >> 4;            // / 16
    const int hbase = (blk & 15) * 64;
    const int t = threadIdx.x;
    const int hl = t & 63;
    const int cq = t >> 6;             // 0..3

    const float* p =
        partial + ((size_t)(b * NCHUNK + cq * 8)) * HH + hbase + hl;
    float acc = 0.f;
    #pragma unroll
    for (int c = 0; c < 8; ++c) acc += p[(size_t)c * HH];

    const float inv = 1.0f / SS;
    if (t >= 64 && t < 192) {
        out[BB * HH + blk * 128 + (t - 64)] = inv;
    }

    __shared__ float lds[4][64];
    lds[cq][hl] = acc;
    __syncthreads();
    if (t < 64) {
        float s = lds[0][t] + lds[1][t] + lds[2][t] + lds[3][t];
        out[b * HH + hbase + t] = s * inv;
    }
}

// Fallback (workspace too small): direct full-column sums.
__global__ void __launch_bounds__(256)
att_direct_kernel(const float* __restrict__ enc, float* __restrict__ out) {
    int tid = blockIdx.x * blockDim.x + threadIdx.x;
    if (tid < BB * HH) {
        int b = tid >> 10;
        int h = tid & (HH - 1);
        const float* p = enc + (size_t)b * SS * HH + h;
        float acc = 0.f;
        for (int s = 0; s < SS; ++s) acc += p[(size_t)s * HH];
        out[tid] = acc * (1.0f / SS);
    } else if (tid < BB * HH + BB * SS) {
        out[tid] = 1.0f / SS;
    }
}

extern "C" void kernel_launch(void* const* d_in, const int* in_sizes, int n_in,
                              void* d_out, int out_size, void* d_ws, size_t ws_size,
                              hipStream_t stream) {
    const float* enc = (const float*)d_in[1];  // encoder_outputs (B,S,H)
    float* out = (float*)d_out;                // [context (B*H) | scores (B*S)]

    const size_t part_bytes = (size_t)NBLK * HH * sizeof(float);  // 1 MiB
    if (d_ws != nullptr && ws_size >= part_bytes) {
        float* partial = (float*)d_ws;
        att_partial_kernel<<<NBLK, 256, 0, stream>>>(enc, partial);
        att_finalize_kernel<<<128, 256, 0, stream>>>(partial, out);
    } else {
        const int total_out = BB * HH + BB * SS;
        att_direct_kernel<<<(total_out + 255) / 256, 256, 0, stream>>>(enc, out);
    }
}

// Round 14
// 16.161 us; speedup vs baseline: 1.1198x; 1.1198x over previous
//
#include <hip/hip_runtime.h>

// (B, S, H) = (8, 2048, 1024), fp32.
// Degenerate math: scores == 1/S exactly (softmax of a constant vector);
// context[b,h] == mean_s enc[b,s,h]; decoder_state cancels entirely.
// Lessons: R2 — grid.sync() ~200us; R3 — contended atomics; R4 — wide
//   finalize; R5 — shallower+more blocks regressed; R6/R9 — SGB & VGPR
//   budget null; R7/R8 — single-dispatch coherence 10x worse; R10 — 512
//   deep blocks + 2 MiB partials: 17.39us BEST; R11 — 256 blocks (1/CU)
//   regressed; R12 — __builtin_nontemporal_load needs native vector type
//   (ext_vector_type), not HIP float4 — fixed here.
// R13: R10 + nontemporal enc loads (fill kernel is write-only = no L2
//   alloc pressure; our 64 MiB read stream thrashes 32 MiB L2 — nt loads
//   skip allocation). Partial path stays cached (reused by kernel B).
#define BB 8
#define SS 2048
#define HH 1024
#define NCHUNK 64            // S-chunks per batch
#define CHUNK (SS / NCHUNK)  // 32 rows per block
#define NBLK (BB * NCHUNK)   // 512 blocks

typedef float vf4 __attribute__((ext_vector_type(4)));

// Kernel A: block g=(b,c) sums its 32-row chunk; thread t owns float4 column
// h=4t..4t+3. 4 passes x 8 independent nontemporal loads, fully unrolled.
__global__ void __launch_bounds__(256, 4)
att_partial_kernel(const float* __restrict__ enc, float* __restrict__ partial) {
    const int g = blockIdx.x;
    const int b = g >> 6;            // / NCHUNK
    const int c = g & (NCHUNK - 1);
    const int t = threadIdx.x;
    const vf4* p =
        (const vf4*)(enc + ((size_t)b * SS + (size_t)c * CHUNK) * HH) + t;

    vf4 acc = (vf4)(0.f);
    #pragma unroll
    for (int pass = 0; pass < 4; ++pass) {
        vf4 v[8];
        #pragma unroll
        for (int s = 0; s < 8; ++s)
            v[s] = __builtin_nontemporal_load(p + (size_t)(pass * 8 + s) * (HH / 4));
        #pragma unroll
        for (int st = 4; st > 0; st >>= 1) {
            #pragma unroll
            for (int s = 0; s < st; ++s) v[s] += v[s + st];
        }
        acc += v[0];
    }
    *((vf4*)(partial + (size_t)g * HH) + t) = acc;  // g == b*NCHUNK + c
}

// Kernel B: 128 blocks x 256 threads. Block = (b, 64-wide h slice); wave cq
// sums chunks c = cq*16..cq*16+15 (coalesced 256 B/wave reads), LDS[4][64]
// cross-wave combine; fills 128 scores per block.
__global__ void __launch_bounds__(256)
att_finalize_kernel(const float* __restrict__ partial, float* __restrict__ out) {
    const int blk = blockIdx.x;        // 0..127
    const int b = blk >> 4;            // / 16
    const int hbase = (blk & 15) * 64;
    const int t = threadIdx.x;
    const int hl = t & 63;
    const int cq = t >> 6;             // 0..3

    const float* p =
        partial + ((size_t)(b * NCHUNK + cq * 16)) * HH + hbase + hl;
    float acc = 0.f;
    #pragma unroll
    for (int c = 0; c < 16; ++c) acc += p[(size_t)c * HH];

    const float inv = 1.0f / SS;
    if (t >= 64 && t < 192) {
        out[BB * HH + blk * 128 + (t - 64)] = inv;
    }

    __shared__ float lds[4][64];
    lds[cq][hl] = acc;
    __syncthreads();
    if (t < 64) {
        float s = lds[0][t] + lds[1][t] + lds[2][t] + lds[3][t];
        out[b * HH + hbase + t] = s * inv;
    }
}

// Fallback (workspace too small): direct full-column sums.
__global__ void __launch_bounds__(256)
att_direct_kernel(const float* __restrict__ enc, float* __restrict__ out) {
    int tid = blockIdx.x * blockDim.x + threadIdx.x;
    if (tid < BB * HH) {
        int b = tid >> 10;
        int h = tid & (HH - 1);
        const float* p = enc + (size_t)b * SS * HH + h;
        float acc = 0.f;
        for (int s = 0; s < SS; ++s) acc += p[(size_t)s * HH];
        out[tid] = acc * (1.0f / SS);
    } else if (tid < BB * HH + BB * SS) {
        out[tid] = 1.0f / SS;
    }
}

extern "C" void kernel_launch(void* const* d_in, const int* in_sizes, int n_in,
                              void* d_out, int out_size, void* d_ws, size_t ws_size,
                              hipStream_t stream) {
    const float* enc = (const float*)d_in[1];  // encoder_outputs (B,S,H)
    float* out = (float*)d_out;                // [context (B*H) | scores (B*S)]

    const size_t part_bytes = (size_t)NBLK * HH * sizeof(float);  // 2 MiB
    if (d_ws != nullptr && ws_size >= part_bytes) {
        float* partial = (float*)d_ws;
        att_partial_kernel<<<NBLK, 256, 0, stream>>>(enc, partial);
        att_finalize_kernel<<<128, 256, 0, stream>>>(partial, out);
    } else {
        const int total_out = BB * HH + BB * SS;
        att_direct_kernel<<<(total_out + 255) / 256, 256, 0, stream>>>(enc, out);
    }
}